// Round 1
// baseline (28910.370 us; speedup 1.0000x reference)
//
#include <hip/hip_runtime.h>

#define T_STEPS 512
#define BATCH   128
#define IND     300
#define KP      320   // K padded to 10*32 for MFMA
#define MEM     512
#define NWG     64    // workgroups in the persistent scan kernel

typedef short bf16x8 __attribute__((ext_vector_type(8)));
typedef float f32x4  __attribute__((ext_vector_type(4)));
typedef unsigned short u16x4 __attribute__((ext_vector_type(4)));

__device__ __forceinline__ unsigned short f2bf(float f){
  unsigned u = __float_as_uint(f);
  u += 0x7FFFu + ((u >> 16) & 1u);           // RNE
  return (unsigned short)(u >> 16);
}
__device__ __forceinline__ float bf2f(unsigned short s){
  return __uint_as_float(((unsigned)s) << 16);
}
__device__ __forceinline__ f32x4 mfma16(bf16x8 a, bf16x8 b, f32x4 c){
  return __builtin_amdgcn_mfma_f32_16x16x32_bf16(a, b, c, 0, 0, 0);
}
__device__ __forceinline__ float sigm(float x){ return 1.0f/(1.0f + __expf(-x)); }
__device__ __forceinline__ float tanh_(float x){
  float t = __expf(-2.0f * fabsf(x));
  float r = (1.0f - t)/(1.0f + t);
  return x < 0.0f ? -r : r;
}

// ---- x fp32 [T,B,300] -> bf16 hi/lo planes [T,B,320] (zero-padded K) ----
__global__ __launch_bounds__(256) void prep_x(const float* __restrict__ x,
                                              unsigned short* __restrict__ xh,
                                              unsigned short* __restrict__ xl){
  long long n = (long long)T_STEPS * BATCH * KP;
  for (long long i = (long long)blockIdx.x * blockDim.x + threadIdx.x; i < n;
       i += (long long)gridDim.x * blockDim.x){
    int k = (int)(i % KP);
    long long tb = i / KP;
    float v = (k < IND) ? x[tb * IND + k] : 0.0f;
    unsigned short h = f2bf(v);
    xh[i] = h;
    xl[i] = f2bf(v - bf2f(h));
  }
}

// ---- P_iou[t][o][b] = x_t[b,:]·W_ioux[o,:] + b_ioux[o] + b_iouh[o], o in [0,1024) ----
// A = x (M=b), B = W slice in LDS (N=o): C col=o => 16B-contiguous stores along b.
__global__ __launch_bounds__(256) void proj_iou(const unsigned short* __restrict__ xh,
                                                const unsigned short* __restrict__ xl,
                                                const float* __restrict__ Wx,
                                                const float* __restrict__ bx,
                                                const float* __restrict__ bh,
                                                float* __restrict__ P){
  const int t = blockIdx.x, obase = blockIdx.y * 64;
  __shared__ unsigned short wh[64*328];
  __shared__ unsigned short wl[64*328];
  for (int idx = threadIdx.x; idx < 64*KP; idx += 256){
    int r = idx / KP, k = idx - r*KP;
    float v = (k < IND) ? Wx[(obase + r)*IND + k] : 0.0f;
    unsigned short hi = f2bf(v);
    wh[r*328 + k] = hi;
    wl[r*328 + k] = f2bf(v - bf2f(hi));
  }
  __syncthreads();
  const int lane = threadIdx.x & 63, w = threadIdx.x >> 6;
  const int l15 = lane & 15, lk = (lane >> 4) << 3, lr4 = (lane >> 4) << 2;
  f32x4 acc[2][4] = {};
  const unsigned short* xbh = xh + (long long)t * BATCH * KP;
  const unsigned short* xbl = xl + (long long)t * BATCH * KP;
  for (int ks = 0; ks < 10; ++ks){
    int k0 = ks*32 + lk;
    bf16x8 ah[2], al[2];
    #pragma unroll
    for (int mt = 0; mt < 2; ++mt){
      int b = w*32 + mt*16 + l15;
      ah[mt] = *(const bf16x8*)(xbh + b*KP + k0);
      al[mt] = *(const bf16x8*)(xbl + b*KP + k0);
    }
    #pragma unroll
    for (int nt = 0; nt < 4; ++nt){
      bf16x8 bh8 = *(const bf16x8*)(wh + (nt*16 + l15)*328 + k0);
      bf16x8 bl8 = *(const bf16x8*)(wl + (nt*16 + l15)*328 + k0);
      #pragma unroll
      for (int mt = 0; mt < 2; ++mt){
        acc[mt][nt] = mfma16(ah[mt], bh8, acc[mt][nt]);
        acc[mt][nt] = mfma16(ah[mt], bl8, acc[mt][nt]);
        acc[mt][nt] = mfma16(al[mt], bh8, acc[mt][nt]);
      }
    }
  }
  #pragma unroll
  for (int nt = 0; nt < 4; ++nt){
    int o = obase + nt*16 + l15;
    float bias = bx[o] + bh[o];
    #pragma unroll
    for (int mt = 0; mt < 2; ++mt){
      int b0 = w*32 + mt*16 + lr4;
      *(f32x4*)(P + ((long long)t*1024 + o)*BATCH + b0) = acc[mt][nt] + bias;
    }
  }
}

// ---- P_f[t][b][m] = x_t[b,:]·W_fx[m,:] + b_fx[m] + b_Uh[m] ----
// A = W slice in LDS (M=m), B = x (N=b): C row=m => 16B-contiguous stores along m.
__global__ __launch_bounds__(256) void proj_f(const unsigned short* __restrict__ xh,
                                              const unsigned short* __restrict__ xl,
                                              const float* __restrict__ Wf,
                                              const float* __restrict__ bf,
                                              const float* __restrict__ bu,
                                              float* __restrict__ Pf){
  const int t = blockIdx.x, mbase = blockIdx.y * 64;
  __shared__ unsigned short wh[64*328];
  __shared__ unsigned short wl[64*328];
  for (int idx = threadIdx.x; idx < 64*KP; idx += 256){
    int r = idx / KP, k = idx - r*KP;
    float v = (k < IND) ? Wf[(mbase + r)*IND + k] : 0.0f;
    unsigned short hi = f2bf(v);
    wh[r*328 + k] = hi;
    wl[r*328 + k] = f2bf(v - bf2f(hi));
  }
  __syncthreads();
  const int lane = threadIdx.x & 63, w = threadIdx.x >> 6;
  const int l15 = lane & 15, lk = (lane >> 4) << 3, lr4 = (lane >> 4) << 2;
  f32x4 acc[4][2] = {};
  const unsigned short* xbh = xh + (long long)t * BATCH * KP;
  const unsigned short* xbl = xl + (long long)t * BATCH * KP;
  for (int ks = 0; ks < 10; ++ks){
    int k0 = ks*32 + lk;
    bf16x8 bh8[2], bl8[2];
    #pragma unroll
    for (int nt = 0; nt < 2; ++nt){
      int b = w*32 + nt*16 + l15;
      bh8[nt] = *(const bf16x8*)(xbh + b*KP + k0);
      bl8[nt] = *(const bf16x8*)(xbl + b*KP + k0);
    }
    #pragma unroll
    for (int mt = 0; mt < 4; ++mt){
      bf16x8 ah = *(const bf16x8*)(wh + (mt*16 + l15)*328 + k0);
      bf16x8 al = *(const bf16x8*)(wl + (mt*16 + l15)*328 + k0);
      #pragma unroll
      for (int nt = 0; nt < 2; ++nt){
        acc[mt][nt] = mfma16(ah, bh8[nt], acc[mt][nt]);
        acc[mt][nt] = mfma16(ah, bl8[nt], acc[mt][nt]);
        acc[mt][nt] = mfma16(al, bh8[nt], acc[mt][nt]);
      }
    }
  }
  #pragma unroll
  for (int mt = 0; mt < 4; ++mt){
    int m0 = mbase + mt*16 + lr4;
    f32x4 bias = *(const f32x4*)(bf + m0);
    f32x4 bias2 = *(const f32x4*)(bu + m0);
    #pragma unroll
    for (int nt = 0; nt < 2; ++nt){
      int b = w*32 + nt*16 + l15;
      *(f32x4*)(Pf + ((long long)t*BATCH + b)*MEM + m0) = acc[mt][nt] + bias + bias2;
    }
  }
}

// ---- persistent GRU scan: 64 WGs x 512 threads, 2 device barriers per step ----
__global__ __launch_bounds__(512) void scan_kernel(
    const float* __restrict__ Wiouh, const float* __restrict__ Wuh,
    const float* __restrict__ Piou, const float* __restrict__ Pf,
    unsigned short* __restrict__ h_hi, unsigned short* __restrict__ h_lo,
    unsigned short* __restrict__ rh_hi, unsigned short* __restrict__ rh_lo,
    float* __restrict__ out, unsigned* __restrict__ bar)
{
  const int g = blockIdx.x;
  const int tid = threadIdx.x;
  const int lane = tid & 63, w = tid >> 6;
  const int l15 = lane & 15, lk = (lane >> 4) << 3, lr4 = (lane >> 4) << 2;

  // weight slices resident in LDS for the whole scan (+8 pad breaks bank conflicts)
  __shared__ unsigned short zr_h[16*520];   // rows 0-7: W_iouh z-slice, 8-15: r-slice
  __shared__ unsigned short zr_l[16*520];
  __shared__ unsigned short wu_h[16*520];   // rows 0-7: W_Uh slice, 8-15: zeros
  __shared__ unsigned short wu_l[16*520];
  __shared__ float          z_lds[BATCH*8]; // z gates, held within owning WG
  __shared__ unsigned short fl_h[BATCH*8];  // rh transpose-staging (hi)
  __shared__ unsigned short fl_l[BATCH*8];  // rh transpose-staging (lo)
  __shared__ float          hn_lds[8*BATCH];// h (own 8 cols) in [m][b] layout, LDS-resident

  for (int idx = tid; idx < 16*512; idx += 512){
    int r = idx >> 9, k = idx & 511;
    float vz = (r < 8) ? Wiouh[(g*8 + r)*512 + k]
                       : Wiouh[(512 + g*8 + (r - 8))*512 + k];
    unsigned short hz = f2bf(vz);
    zr_h[r*520 + k] = hz;
    zr_l[r*520 + k] = f2bf(vz - bf2f(hz));
    float vu = (r < 8) ? Wuh[(g*8 + r)*512 + k] : 0.0f;
    unsigned short hu = f2bf(vu);
    wu_h[r*520 + k] = hu;
    wu_l[r*520 + k] = f2bf(vu - bf2f(hu));
  }
  for (int idx = tid; idx < 8*BATCH; idx += 512) hn_lds[idx] = 0.0f;
  __syncthreads();

  const bool is_z = (l15 < 8);
  const int o_p = is_z ? (g*8 + l15) : (512 + g*8 + (l15 - 8)); // P_iou row
  const bool valid2 = (lane >> 4) < 2;
  unsigned gen = 0;

  for (int t = 0; t < T_STEPS; ++t){
    const int b0 = w*16 + lr4;
    // prefetch stable x-projection operand for the phase-1 epilogue
    f32x4 p1 = *(const f32x4*)(Piou + ((long long)t*1024 + o_p)*BATCH + b0);

    // ---- phase 1: iou = h @ W_zr^T (A=h from global/L2, B=weights from LDS) ----
    f32x4 acc1 = {0.f,0.f,0.f,0.f};
    const int brow = w*16 + l15;
    for (int ks = 0; ks < 16; ++ks){
      int k0 = ks*32 + lk;
      bf16x8 a_h = *(const bf16x8*)(h_hi + brow*MEM + k0);
      bf16x8 a_l = *(const bf16x8*)(h_lo + brow*MEM + k0);
      bf16x8 b_h = *(const bf16x8*)(zr_h + l15*520 + k0);
      bf16x8 b_l = *(const bf16x8*)(zr_l + l15*520 + k0);
      acc1 = mfma16(a_h, b_h, acc1);
      acc1 = mfma16(a_h, b_l, acc1);
      acc1 = mfma16(a_l, b_h, acc1);
    }
    if (is_z){
      #pragma unroll
      for (int j = 0; j < 4; ++j){
        float zv = sigm(acc1[j] + p1[j]);
        z_lds[(b0 + j)*8 + l15] = zv;
      }
    } else {
      f32x4 hold = *(const f32x4*)(&hn_lds[(l15 - 8)*BATCH + b0]);
      #pragma unroll
      for (int j = 0; j < 4; ++j){
        float rv = sigm(acc1[j] + p1[j]);
        float rh = rv * hold[j];
        unsigned short hi = f2bf(rh);
        fl_h[(b0 + j)*8 + (l15 - 8)] = hi;
        fl_l[(b0 + j)*8 + (l15 - 8)] = f2bf(rh - bf2f(hi));
      }
    }
    __syncthreads();
    // cooperative vectorized flush of rh slice to global (16B stores)
    if (tid < 256){
      int b = tid >> 1, pl = tid & 1;
      bf16x8 v = *(const bf16x8*)((pl ? fl_l : fl_h) + b*8);
      *(bf16x8*)((pl ? rh_lo : rh_hi) + b*MEM + g*8) = v;
    }
    __threadfence();
    __syncthreads();
    gen++;
    if (tid == 0) __hip_atomic_fetch_add(bar, 1u, __ATOMIC_ACQ_REL, __HIP_MEMORY_SCOPE_AGENT);
    // prefetch stable P_f while the barrier settles
    f32x4 p2 = {0.f,0.f,0.f,0.f};
    const int b2 = w*16 + l15;
    const int m0g = g*8 + lr4;
    if (valid2) p2 = *(const f32x4*)(Pf + ((long long)t*BATCH + b2)*MEM + m0g);
    if (tid == 0){
      unsigned tgt = gen * NWG;
      while (__hip_atomic_load(bar, __ATOMIC_ACQUIRE, __HIP_MEMORY_SCOPE_AGENT) < tgt)
        __builtin_amdgcn_s_sleep(1);
    }
    __syncthreads();

    // ---- phase 2: u = rh @ W_U^T with swapped roles (A=W_U LDS, B=rh global) ----
    f32x4 acc2 = {0.f,0.f,0.f,0.f};
    for (int ks = 0; ks < 16; ++ks){
      int k0 = ks*32 + lk;
      bf16x8 a_h = *(const bf16x8*)(wu_h + l15*520 + k0);
      bf16x8 a_l = *(const bf16x8*)(wu_l + l15*520 + k0);
      bf16x8 b_h = *(const bf16x8*)(rh_hi + b2*MEM + k0);
      bf16x8 b_l = *(const bf16x8*)(rh_lo + b2*MEM + k0);
      acc2 = mfma16(a_h, b_h, acc2);
      acc2 = mfma16(a_h, b_l, acc2);
      acc2 = mfma16(a_l, b_h, acc2);
    }
    if (valid2){
      u16x4 hh = *(const u16x4*)(h_hi + b2*MEM + m0g);
      u16x4 hl = *(const u16x4*)(h_lo + b2*MEM + m0g);
      f32x4 zz = *(const f32x4*)(&z_lds[b2*8 + lr4]);
      f32x4 hn;
      u16x4 nh, nl;
      #pragma unroll
      for (int j = 0; j < 4; ++j){
        float h_old = bf2f(hh[j]) + bf2f(hl[j]);
        float ht = tanh_(acc2[j] + p2[j]);
        float hv = (1.0f - zz[j])*h_old + zz[j]*ht;
        hn[j] = hv;
        unsigned short nhi = f2bf(hv);
        nh[j] = nhi;
        nl[j] = f2bf(hv - bf2f(nhi));
        hn_lds[(lr4 + j)*BATCH + b2] = hv;
      }
      *(f32x4*)(out + ((long long)t*BATCH + b2)*MEM + m0g) = hn;
      *(u16x4*)(h_hi + b2*MEM + m0g) = nh;
      *(u16x4*)(h_lo + b2*MEM + m0g) = nl;
    }
    __threadfence();
    __syncthreads();
    gen++;
    if (tid == 0) __hip_atomic_fetch_add(bar, 1u, __ATOMIC_ACQ_REL, __HIP_MEMORY_SCOPE_AGENT);
    if (tid == 0){
      unsigned tgt = gen * NWG;
      while (__hip_atomic_load(bar, __ATOMIC_ACQUIRE, __HIP_MEMORY_SCOPE_AGENT) < tgt)
        __builtin_amdgcn_s_sleep(1);
    }
    __syncthreads();
  }
}

extern "C" void kernel_launch(void* const* d_in, const int* in_sizes, int n_in,
                              void* d_out, int out_size, void* d_ws, size_t ws_size,
                              hipStream_t stream){
  (void)in_sizes; (void)n_in; (void)out_size; (void)ws_size;
  const float* x     = (const float*)d_in[0];
  const float* Wioux = (const float*)d_in[1];
  const float* bioux = (const float*)d_in[2];
  const float* Wiouh = (const float*)d_in[3];
  const float* biouh = (const float*)d_in[4];
  const float* Wfx   = (const float*)d_in[5];
  const float* bfx   = (const float*)d_in[6];
  const float* Wuh   = (const float*)d_in[7];
  const float* buh   = (const float*)d_in[8];
  float* out = (float*)d_out;

  char* ws = (char*)d_ws;
  size_t off = 0;
  auto alloc = [&](size_t bytes) -> void* {
    void* p = ws + off;
    off += (bytes + 255) & ~(size_t)255;
    return p;
  };
  float* Piou = (float*)alloc((size_t)T_STEPS*1024*BATCH*sizeof(float)); // 268 MB
  float* Pf   = (float*)alloc((size_t)T_STEPS*BATCH*MEM*sizeof(float));  // 134 MB
  unsigned short* xh = (unsigned short*)alloc((size_t)T_STEPS*BATCH*KP*2); // 42 MB
  unsigned short* xl = (unsigned short*)alloc((size_t)T_STEPS*BATCH*KP*2); // 42 MB
  unsigned short* hhi  = (unsigned short*)alloc(BATCH*MEM*2);
  unsigned short* hlo  = (unsigned short*)alloc(BATCH*MEM*2);
  unsigned short* rhhi = (unsigned short*)alloc(BATCH*MEM*2);
  unsigned short* rhlo = (unsigned short*)alloc(BATCH*MEM*2);
  unsigned* bar = (unsigned*)alloc(256);

  hipMemsetAsync(hhi, 0, BATCH*MEM*2, stream);   // h0 = 0
  hipMemsetAsync(hlo, 0, BATCH*MEM*2, stream);
  hipMemsetAsync(bar, 0, 256, stream);           // barrier counter

  prep_x<<<2048, 256, 0, stream>>>(x, xh, xl);
  proj_iou<<<dim3(T_STEPS, 16), 256, 0, stream>>>(xh, xl, Wioux, bioux, biouh, Piou);
  proj_f<<<dim3(T_STEPS, 8), 256, 0, stream>>>(xh, xl, Wfx, bfx, buh, Pf);
  scan_kernel<<<NWG, 512, 0, stream>>>(Wiouh, Wuh, Piou, Pf, hhi, hlo, rhhi, rhlo, out, bar);
}

// Round 2
// 19204.732 us; speedup vs baseline: 1.5054x; 1.5054x over previous
//
#include <hip/hip_runtime.h>

#define T_STEPS 512
#define BATCH   128
#define IND     300
#define KP      320   // K padded to 10*32 for MFMA
#define MEM     512
#define NWG     64    // workgroups in the persistent scan kernel

typedef short bf16x8 __attribute__((ext_vector_type(8)));
typedef float f32x4  __attribute__((ext_vector_type(4)));
typedef unsigned short u16x4 __attribute__((ext_vector_type(4)));

__device__ __forceinline__ unsigned short f2bf(float f){
  unsigned u = __float_as_uint(f);
  u += 0x7FFFu + ((u >> 16) & 1u);           // RNE
  return (unsigned short)(u >> 16);
}
__device__ __forceinline__ float bf2f(unsigned short s){
  return __uint_as_float(((unsigned)s) << 16);
}
__device__ __forceinline__ f32x4 mfma16(bf16x8 a, bf16x8 b, f32x4 c){
  return __builtin_amdgcn_mfma_f32_16x16x32_bf16(a, b, c, 0, 0, 0);
}
__device__ __forceinline__ float sigm(float x){ return 1.0f/(1.0f + __expf(-x)); }
__device__ __forceinline__ float tanh_(float x){
  float t = __expf(-2.0f * fabsf(x));
  float r = (1.0f - t)/(1.0f + t);
  return x < 0.0f ? -r : r;
}

// ---- device-coherent (MALL) data plane: relaxed system-scope atomics ----
// Compile to global_load/store sc0 sc1 (bypass L1+L2, served by Infinity Cache).
// RELAXED => NO buffer_wbl2 / buffer_inv cache-maintenance instructions.
__device__ __forceinline__ unsigned long long ld8_sc(const void* p){
  return __hip_atomic_load((const unsigned long long*)p, __ATOMIC_RELAXED,
                           __HIP_MEMORY_SCOPE_SYSTEM);
}
__device__ __forceinline__ void st8_sc(void* p, unsigned long long v){
  __hip_atomic_store((unsigned long long*)p, v, __ATOMIC_RELAXED,
                     __HIP_MEMORY_SCOPE_SYSTEM);
}
__device__ __forceinline__ bf16x8 ld_bf8_sc(const unsigned short* p){
  union { unsigned long long q[2]; bf16x8 v; } u;
  u.q[0] = ld8_sc(p);
  u.q[1] = ld8_sc(p + 4);
  return u.v;
}

// ---- x fp32 [T,B,300] -> bf16 hi/lo planes [T,B,320] (zero-padded K) ----
__global__ __launch_bounds__(256) void prep_x(const float* __restrict__ x,
                                              unsigned short* __restrict__ xh,
                                              unsigned short* __restrict__ xl){
  long long n = (long long)T_STEPS * BATCH * KP;
  for (long long i = (long long)blockIdx.x * blockDim.x + threadIdx.x; i < n;
       i += (long long)gridDim.x * blockDim.x){
    int k = (int)(i % KP);
    long long tb = i / KP;
    float v = (k < IND) ? x[tb * IND + k] : 0.0f;
    unsigned short h = f2bf(v);
    xh[i] = h;
    xl[i] = f2bf(v - bf2f(h));
  }
}

// ---- P_iou[t][o][b] = x_t[b,:]·W_ioux[o,:] + b_ioux[o] + b_iouh[o], o in [0,1024) ----
__global__ __launch_bounds__(256) void proj_iou(const unsigned short* __restrict__ xh,
                                                const unsigned short* __restrict__ xl,
                                                const float* __restrict__ Wx,
                                                const float* __restrict__ bx,
                                                const float* __restrict__ bh,
                                                float* __restrict__ P){
  const int t = blockIdx.x, obase = blockIdx.y * 64;
  __shared__ unsigned short wh[64*328];
  __shared__ unsigned short wl[64*328];
  for (int idx = threadIdx.x; idx < 64*KP; idx += 256){
    int r = idx / KP, k = idx - r*KP;
    float v = (k < IND) ? Wx[(obase + r)*IND + k] : 0.0f;
    unsigned short hi = f2bf(v);
    wh[r*328 + k] = hi;
    wl[r*328 + k] = f2bf(v - bf2f(hi));
  }
  __syncthreads();
  const int lane = threadIdx.x & 63, w = threadIdx.x >> 6;
  const int l15 = lane & 15, lk = (lane >> 4) << 3, lr4 = (lane >> 4) << 2;
  f32x4 acc[2][4] = {};
  const unsigned short* xbh = xh + (long long)t * BATCH * KP;
  const unsigned short* xbl = xl + (long long)t * BATCH * KP;
  for (int ks = 0; ks < 10; ++ks){
    int k0 = ks*32 + lk;
    bf16x8 ah[2], al[2];
    #pragma unroll
    for (int mt = 0; mt < 2; ++mt){
      int b = w*32 + mt*16 + l15;
      ah[mt] = *(const bf16x8*)(xbh + b*KP + k0);
      al[mt] = *(const bf16x8*)(xbl + b*KP + k0);
    }
    #pragma unroll
    for (int nt = 0; nt < 4; ++nt){
      bf16x8 bh8 = *(const bf16x8*)(wh + (nt*16 + l15)*328 + k0);
      bf16x8 bl8 = *(const bf16x8*)(wl + (nt*16 + l15)*328 + k0);
      #pragma unroll
      for (int mt = 0; mt < 2; ++mt){
        acc[mt][nt] = mfma16(ah[mt], bh8, acc[mt][nt]);
        acc[mt][nt] = mfma16(ah[mt], bl8, acc[mt][nt]);
        acc[mt][nt] = mfma16(al[mt], bh8, acc[mt][nt]);
      }
    }
  }
  #pragma unroll
  for (int nt = 0; nt < 4; ++nt){
    int o = obase + nt*16 + l15;
    float bias = bx[o] + bh[o];
    #pragma unroll
    for (int mt = 0; mt < 2; ++mt){
      int b0 = w*32 + mt*16 + lr4;
      *(f32x4*)(P + ((long long)t*1024 + o)*BATCH + b0) = acc[mt][nt] + bias;
    }
  }
}

// ---- P_f[t][b][m] = x_t[b,:]·W_fx[m,:] + b_fx[m] + b_Uh[m] ----
__global__ __launch_bounds__(256) void proj_f(const unsigned short* __restrict__ xh,
                                              const unsigned short* __restrict__ xl,
                                              const float* __restrict__ Wf,
                                              const float* __restrict__ bf,
                                              const float* __restrict__ bu,
                                              float* __restrict__ Pf){
  const int t = blockIdx.x, mbase = blockIdx.y * 64;
  __shared__ unsigned short wh[64*328];
  __shared__ unsigned short wl[64*328];
  for (int idx = threadIdx.x; idx < 64*KP; idx += 256){
    int r = idx / KP, k = idx - r*KP;
    float v = (k < IND) ? Wf[(mbase + r)*IND + k] : 0.0f;
    unsigned short hi = f2bf(v);
    wh[r*328 + k] = hi;
    wl[r*328 + k] = f2bf(v - bf2f(hi));
  }
  __syncthreads();
  const int lane = threadIdx.x & 63, w = threadIdx.x >> 6;
  const int l15 = lane & 15, lk = (lane >> 4) << 3, lr4 = (lane >> 4) << 2;
  f32x4 acc[4][2] = {};
  const unsigned short* xbh = xh + (long long)t * BATCH * KP;
  const unsigned short* xbl = xl + (long long)t * BATCH * KP;
  for (int ks = 0; ks < 10; ++ks){
    int k0 = ks*32 + lk;
    bf16x8 bh8[2], bl8[2];
    #pragma unroll
    for (int nt = 0; nt < 2; ++nt){
      int b = w*32 + nt*16 + l15;
      bh8[nt] = *(const bf16x8*)(xbh + b*KP + k0);
      bl8[nt] = *(const bf16x8*)(xbl + b*KP + k0);
    }
    #pragma unroll
    for (int mt = 0; mt < 4; ++mt){
      bf16x8 ah = *(const bf16x8*)(wh + (mt*16 + l15)*328 + k0);
      bf16x8 al = *(const bf16x8*)(wl + (mt*16 + l15)*328 + k0);
      #pragma unroll
      for (int nt = 0; nt < 2; ++nt){
        acc[mt][nt] = mfma16(ah, bh8[nt], acc[mt][nt]);
        acc[mt][nt] = mfma16(ah, bl8[nt], acc[mt][nt]);
        acc[mt][nt] = mfma16(al, bh8[nt], acc[mt][nt]);
      }
    }
  }
  #pragma unroll
  for (int mt = 0; mt < 4; ++mt){
    int m0 = mbase + mt*16 + lr4;
    f32x4 bias = *(const f32x4*)(bf + m0);
    f32x4 bias2 = *(const f32x4*)(bu + m0);
    #pragma unroll
    for (int nt = 0; nt < 2; ++nt){
      int b = w*32 + nt*16 + l15;
      *(f32x4*)(Pf + ((long long)t*BATCH + b)*MEM + m0) = acc[mt][nt] + bias + bias2;
    }
  }
}

// ---- persistent GRU scan: 64 WGs x 512 threads, 2 fence-free barriers per step ----
__global__ __launch_bounds__(512) void scan_kernel(
    const float* __restrict__ Wiouh, const float* __restrict__ Wuh,
    const float* __restrict__ Piou, const float* __restrict__ Pf,
    unsigned short* __restrict__ h_hi, unsigned short* __restrict__ h_lo,
    unsigned short* __restrict__ rh_hi, unsigned short* __restrict__ rh_lo,
    float* __restrict__ out, unsigned* __restrict__ bar)
{
  const int g = blockIdx.x;
  const int tid = threadIdx.x;
  const int lane = tid & 63, w = tid >> 6;
  const int l15 = lane & 15, lk = (lane >> 4) << 3, lr4 = (lane >> 4) << 2;

  __shared__ unsigned short zr_h[16*520];   // rows 0-7: W_iouh z-slice, 8-15: r-slice
  __shared__ unsigned short zr_l[16*520];
  __shared__ unsigned short wu_h[16*520];   // rows 0-7: W_Uh slice, 8-15: zeros
  __shared__ unsigned short wu_l[16*520];
  __shared__ float          z_lds[BATCH*8]; // z gates, WG-local
  __shared__ unsigned short fl_h[BATCH*8];  // rh transpose-staging (hi)
  __shared__ unsigned short fl_l[BATCH*8];  // rh transpose-staging (lo)
  __shared__ float          hn_lds[8*BATCH];// own 8 h-cols in [m][b], fp32 exact

  for (int idx = tid; idx < 16*512; idx += 512){
    int r = idx >> 9, k = idx & 511;
    float vz = (r < 8) ? Wiouh[(g*8 + r)*512 + k]
                       : Wiouh[(512 + g*8 + (r - 8))*512 + k];
    unsigned short hz = f2bf(vz);
    zr_h[r*520 + k] = hz;
    zr_l[r*520 + k] = f2bf(vz - bf2f(hz));
    float vu = (r < 8) ? Wuh[(g*8 + r)*512 + k] : 0.0f;
    unsigned short hu = f2bf(vu);
    wu_h[r*520 + k] = hu;
    wu_l[r*520 + k] = f2bf(vu - bf2f(hu));
  }
  for (int idx = tid; idx < 8*BATCH; idx += 512) hn_lds[idx] = 0.0f;
  __syncthreads();

  const bool is_z = (l15 < 8);
  const int o_p = is_z ? (g*8 + l15) : (512 + g*8 + (l15 - 8)); // P_iou row
  const bool valid2 = (lane >> 4) < 2;
  const int b0 = w*16 + lr4;
  const int b2 = w*16 + l15;
  const int m0g = g*8 + lr4;
  unsigned gen = 0;

  f32x4 p1 = *(const f32x4*)(Piou + (long long)o_p*BATCH + b0);  // t = 0

  for (int t = 0; t < T_STEPS; ++t){
    // ---- phase 1: iou = h @ W_zr^T (A=h via MALL, B=weights in LDS) ----
    f32x4 acc1 = {0.f,0.f,0.f,0.f};
    #pragma unroll 4
    for (int ks = 0; ks < 16; ++ks){
      int k0 = ks*32 + lk;
      bf16x8 a_h = ld_bf8_sc(h_hi + b2*MEM + k0);
      bf16x8 a_l = ld_bf8_sc(h_lo + b2*MEM + k0);
      bf16x8 b_h = *(const bf16x8*)(zr_h + l15*520 + k0);
      bf16x8 b_l = *(const bf16x8*)(zr_l + l15*520 + k0);
      acc1 = mfma16(a_h, b_h, acc1);
      acc1 = mfma16(a_h, b_l, acc1);
      acc1 = mfma16(a_l, b_h, acc1);
    }
    if (is_z){
      #pragma unroll
      for (int j = 0; j < 4; ++j){
        float zv = sigm(acc1[j] + p1[j]);
        z_lds[(b0 + j)*8 + l15] = zv;
      }
    } else {
      #pragma unroll
      for (int j = 0; j < 4; ++j){
        float rv = sigm(acc1[j] + p1[j]);
        float rh = rv * hn_lds[(l15 - 8)*BATCH + b0 + j];
        unsigned short hi = f2bf(rh);
        fl_h[(b0 + j)*8 + (l15 - 8)] = hi;
        fl_l[(b0 + j)*8 + (l15 - 8)] = f2bf(rh - bf2f(hi));
      }
    }
    __syncthreads();
    // cooperative flush of rh slice to MALL (512 x 8B write-through stores)
    {
      int b = tid >> 2, q = tid & 3;
      const unsigned short* src = (q >> 1) ? fl_l : fl_h;
      unsigned short* dst = (q >> 1) ? rh_lo : rh_hi;
      unsigned long long v = *(const unsigned long long*)(src + b*8 + (q&1)*4);
      st8_sc(dst + b*MEM + g*8 + (q&1)*4, v);
    }
    __syncthreads();   // emits s_waitcnt vmcnt(0) per wave before s_barrier => stores drained
    if (tid == 0) __hip_atomic_fetch_add(bar, 1u, __ATOMIC_RELAXED, __HIP_MEMORY_SCOPE_SYSTEM);
    f32x4 p2 = {0.f,0.f,0.f,0.f};
    if (valid2) p2 = *(const f32x4*)(Pf + ((long long)t*BATCH + b2)*MEM + m0g);
    ++gen;
    if (tid == 0){
      unsigned tgt = gen * NWG;
      while (__hip_atomic_load(bar, __ATOMIC_RELAXED, __HIP_MEMORY_SCOPE_SYSTEM) < tgt)
        __builtin_amdgcn_s_sleep(2);
    }
    __syncthreads();
    asm volatile("" ::: "memory");

    // ---- phase 2: u = rh @ W_U^T (A=W_U in LDS, B=rh via MALL) ----
    f32x4 acc2 = {0.f,0.f,0.f,0.f};
    #pragma unroll 4
    for (int ks = 0; ks < 16; ++ks){
      int k0 = ks*32 + lk;
      bf16x8 a_h = *(const bf16x8*)(wu_h + l15*520 + k0);
      bf16x8 a_l = *(const bf16x8*)(wu_l + l15*520 + k0);
      bf16x8 b_h = ld_bf8_sc(rh_hi + b2*MEM + k0);
      bf16x8 b_l = ld_bf8_sc(rh_lo + b2*MEM + k0);
      acc2 = mfma16(a_h, b_h, acc2);
      acc2 = mfma16(a_h, b_l, acc2);
      acc2 = mfma16(a_l, b_h, acc2);
    }
    if (valid2){
      f32x4 zz = *(const f32x4*)(&z_lds[b2*8 + lr4]);
      f32x4 hn;
      u16x4 nh, nl;
      #pragma unroll
      for (int j = 0; j < 4; ++j){
        float h_old = hn_lds[(lr4 + j)*BATCH + b2];   // fp32-exact own copy
        float ht = tanh_(acc2[j] + p2[j]);
        float hv = (1.0f - zz[j])*h_old + zz[j]*ht;
        hn[j] = hv;
        unsigned short nhi = f2bf(hv);
        nh[j] = nhi;
        nl[j] = f2bf(hv - bf2f(nhi));
        hn_lds[(lr4 + j)*BATCH + b2] = hv;
      }
      *(f32x4*)(out + ((long long)t*BATCH + b2)*MEM + m0g) = hn;
      union { u16x4 s; unsigned long long q; } uh, ul;
      uh.s = nh; ul.s = nl;
      st8_sc(h_hi + b2*MEM + m0g, uh.q);
      st8_sc(h_lo + b2*MEM + m0g, ul.q);
    }
    __syncthreads();   // drains h stores (per-wave vmcnt(0) before s_barrier)
    if (tid == 0) __hip_atomic_fetch_add(bar, 1u, __ATOMIC_RELAXED, __HIP_MEMORY_SCOPE_SYSTEM);
    ++gen;
    if (t + 1 < T_STEPS)
      p1 = *(const f32x4*)(Piou + ((long long)(t+1)*1024 + o_p)*BATCH + b0);
    if (tid == 0){
      unsigned tgt = gen * NWG;
      while (__hip_atomic_load(bar, __ATOMIC_RELAXED, __HIP_MEMORY_SCOPE_SYSTEM) < tgt)
        __builtin_amdgcn_s_sleep(2);
    }
    __syncthreads();
    asm volatile("" ::: "memory");
  }
}

extern "C" void kernel_launch(void* const* d_in, const int* in_sizes, int n_in,
                              void* d_out, int out_size, void* d_ws, size_t ws_size,
                              hipStream_t stream){
  (void)in_sizes; (void)n_in; (void)out_size; (void)ws_size;
  const float* x     = (const float*)d_in[0];
  const float* Wioux = (const float*)d_in[1];
  const float* bioux = (const float*)d_in[2];
  const float* Wiouh = (const float*)d_in[3];
  const float* biouh = (const float*)d_in[4];
  const float* Wfx   = (const float*)d_in[5];
  const float* bfx   = (const float*)d_in[6];
  const float* Wuh   = (const float*)d_in[7];
  const float* buh   = (const float*)d_in[8];
  float* out = (float*)d_out;

  char* ws = (char*)d_ws;
  size_t off = 0;
  auto alloc = [&](size_t bytes) -> void* {
    void* p = ws + off;
    off += (bytes + 255) & ~(size_t)255;
    return p;
  };
  float* Piou = (float*)alloc((size_t)T_STEPS*1024*BATCH*sizeof(float)); // 268 MB
  float* Pf   = (float*)alloc((size_t)T_STEPS*BATCH*MEM*sizeof(float));  // 134 MB
  unsigned short* xh = (unsigned short*)alloc((size_t)T_STEPS*BATCH*KP*2); // 42 MB
  unsigned short* xl = (unsigned short*)alloc((size_t)T_STEPS*BATCH*KP*2); // 42 MB
  unsigned short* hhi  = (unsigned short*)alloc(BATCH*MEM*2);
  unsigned short* hlo  = (unsigned short*)alloc(BATCH*MEM*2);
  unsigned short* rhhi = (unsigned short*)alloc(BATCH*MEM*2);
  unsigned short* rhlo = (unsigned short*)alloc(BATCH*MEM*2);
  unsigned* bar = (unsigned*)alloc(256);

  hipMemsetAsync(hhi, 0, BATCH*MEM*2, stream);   // h0 = 0
  hipMemsetAsync(hlo, 0, BATCH*MEM*2, stream);
  hipMemsetAsync(bar, 0, 256, stream);           // barrier counter

  prep_x<<<2048, 256, 0, stream>>>(x, xh, xl);
  proj_iou<<<dim3(T_STEPS, 16), 256, 0, stream>>>(xh, xl, Wioux, bioux, biouh, Piou);
  proj_f<<<dim3(T_STEPS, 8), 256, 0, stream>>>(xh, xl, Wfx, bfx, buh, Pf);
  scan_kernel<<<NWG, 512, 0, stream>>>(Wiouh, Wuh, Piou, Pf, hhi, hlo, rhhi, rhlo, out, bar);
}

// Round 4
// 12037.256 us; speedup vs baseline: 2.4017x; 1.5954x over previous
//
#include <hip/hip_runtime.h>

#define T_STEPS 512
#define BATCH   128
#define IND     300
#define KP      320   // K padded to 10*32 for MFMA
#define MEM     512
#define NWG     64    // workgroups in the persistent scan kernel

typedef short bf16x8 __attribute__((ext_vector_type(8)));
typedef float f32x4  __attribute__((ext_vector_type(4)));
typedef unsigned short u16x4 __attribute__((ext_vector_type(4)));

__device__ __forceinline__ unsigned short f2bf(float f){
  unsigned u = __float_as_uint(f);
  u += 0x7FFFu + ((u >> 16) & 1u);           // RNE
  return (unsigned short)(u >> 16);
}
__device__ __forceinline__ float bf2f(unsigned short s){
  return __uint_as_float(((unsigned)s) << 16);
}
__device__ __forceinline__ f32x4 mfma16(bf16x8 a, bf16x8 b, f32x4 c){
  return __builtin_amdgcn_mfma_f32_16x16x32_bf16(a, b, c, 0, 0, 0);
}
__device__ __forceinline__ float sigm(float x){ return 1.0f/(1.0f + __expf(-x)); }
__device__ __forceinline__ float tanh_(float x){
  float t = __expf(-2.0f * fabsf(x));
  float r = (1.0f - t)/(1.0f + t);
  return x < 0.0f ? -r : r;
}

// ---- MALL-coherent scalar ops (verified working in round 2) ----
__device__ __forceinline__ void st8_sc(void* p, unsigned long long v){
  __hip_atomic_store((unsigned long long*)p, v, __ATOMIC_RELAXED,
                     __HIP_MEMORY_SCOPE_SYSTEM);
}
__device__ __forceinline__ void st4_sc(unsigned* p, unsigned v){
  __hip_atomic_store(p, v, __ATOMIC_RELAXED, __HIP_MEMORY_SCOPE_SYSTEM);
}
__device__ __forceinline__ unsigned ld4_sc(const unsigned* p){
  return __hip_atomic_load(p, __ATOMIC_RELAXED, __HIP_MEMORY_SCOPE_SYSTEM);
}

// ---- batched MALL loads: 32 x global_load_dwordx4 sc0 sc1 from one base ----
// Row layout: [128][1024] ushort, row = hi[0..511] ++ lo[0..511], so all 32
// fragments live within byte offsets 0..1984+16 of (row base + lk) -> imm offsets.
#define G16(i, ofs) "global_load_dwordx4 %" #i ", %16, off offset:" #ofs " sc0 sc1\n\t"
__device__ __forceinline__ void ld_row_batch(const unsigned short* p,
                                             bf16x8* A, bf16x8* B){
  asm volatile(
    G16(0,0)    G16(1,64)   G16(2,128)  G16(3,192)
    G16(4,256)  G16(5,320)  G16(6,384)  G16(7,448)
    G16(8,512)  G16(9,576)  G16(10,640) G16(11,704)
    G16(12,768) G16(13,832) G16(14,896) G16(15,960)
    : "=&v"(A[0]),"=&v"(A[1]),"=&v"(A[2]),"=&v"(A[3]),
      "=&v"(A[4]),"=&v"(A[5]),"=&v"(A[6]),"=&v"(A[7]),
      "=&v"(A[8]),"=&v"(A[9]),"=&v"(A[10]),"=&v"(A[11]),
      "=&v"(A[12]),"=&v"(A[13]),"=&v"(A[14]),"=&v"(A[15])
    : "v"(p));
  asm volatile(
    G16(0,1024) G16(1,1088) G16(2,1152) G16(3,1216)
    G16(4,1280) G16(5,1344) G16(6,1408) G16(7,1472)
    G16(8,1536) G16(9,1600) G16(10,1664) G16(11,1728)
    G16(12,1792) G16(13,1856) G16(14,1920) G16(15,1984)
    : "=&v"(B[0]),"=&v"(B[1]),"=&v"(B[2]),"=&v"(B[3]),
      "=&v"(B[4]),"=&v"(B[5]),"=&v"(B[6]),"=&v"(B[7]),
      "=&v"(B[8]),"=&v"(B[9]),"=&v"(B[10]),"=&v"(B[11]),
      "=&v"(B[12]),"=&v"(B[13]),"=&v"(B[14]),"=&v"(B[15])
    : "v"(p));
}

// ---- x fp32 [T,B,300] -> bf16 hi/lo planes [T,B,320] ----
__global__ __launch_bounds__(256) void prep_x(const float* __restrict__ x,
                                              unsigned short* __restrict__ xh,
                                              unsigned short* __restrict__ xl){
  long long n = (long long)T_STEPS * BATCH * KP;
  for (long long i = (long long)blockIdx.x * blockDim.x + threadIdx.x; i < n;
       i += (long long)gridDim.x * blockDim.x){
    int k = (int)(i % KP);
    long long tb = i / KP;
    float v = (k < IND) ? x[tb * IND + k] : 0.0f;
    unsigned short h = f2bf(v);
    xh[i] = h;
    xl[i] = f2bf(v - bf2f(h));
  }
}

// ---- one-shot W_ioux/W_fx fp32 -> bf16 hi/lo [1536][320] (rows 0-1023 iou, 1024-1535 f) ----
__global__ __launch_bounds__(256) void prep_w(const float* __restrict__ Wioux,
                                              const float* __restrict__ Wfx,
                                              unsigned short* __restrict__ wxh,
                                              unsigned short* __restrict__ wxl){
  int n = 1536 * KP;
  for (int i = blockIdx.x * blockDim.x + threadIdx.x; i < n;
       i += gridDim.x * blockDim.x){
    int k = i % KP, row = i / KP;
    float v = 0.0f;
    if (k < IND) v = (row < 1024) ? Wioux[row*IND + k] : Wfx[(row-1024)*IND + k];
    unsigned short h = f2bf(v);
    wxh[i] = h;
    wxl[i] = f2bf(v - bf2f(h));
  }
}

// ---- P_iou[t][o][b] = x_t[b,:]·W_ioux[o,:] + b_ioux[o] + b_iouh[o] ----
__global__ __launch_bounds__(256) void proj_iou(const unsigned short* __restrict__ xh,
                                                const unsigned short* __restrict__ xl,
                                                const unsigned short* __restrict__ wxh,
                                                const unsigned short* __restrict__ wxl,
                                                const float* __restrict__ bx,
                                                const float* __restrict__ bh,
                                                float* __restrict__ P){
  const int t = blockIdx.x, obase = blockIdx.y * 64;
  __shared__ unsigned short wh[64*328];
  __shared__ unsigned short wl[64*328];
  for (int c = threadIdx.x; c < 64*40; c += 256){
    int r = c / 40, c8 = (c % 40) * 8;
    *(bf16x8*)(wh + r*328 + c8) = *(const bf16x8*)(wxh + (obase + r)*KP + c8);
    *(bf16x8*)(wl + r*328 + c8) = *(const bf16x8*)(wxl + (obase + r)*KP + c8);
  }
  __syncthreads();
  const int lane = threadIdx.x & 63, w = threadIdx.x >> 6;
  const int l15 = lane & 15, lk = (lane >> 4) << 3, lr4 = (lane >> 4) << 2;
  f32x4 acc[2][4] = {};
  const unsigned short* xbh = xh + (long long)t * BATCH * KP;
  const unsigned short* xbl = xl + (long long)t * BATCH * KP;
  for (int ks = 0; ks < 10; ++ks){
    int k0 = ks*32 + lk;
    bf16x8 ah[2], al[2];
    #pragma unroll
    for (int mt = 0; mt < 2; ++mt){
      int b = w*32 + mt*16 + l15;
      ah[mt] = *(const bf16x8*)(xbh + b*KP + k0);
      al[mt] = *(const bf16x8*)(xbl + b*KP + k0);
    }
    #pragma unroll
    for (int nt = 0; nt < 4; ++nt){
      bf16x8 bh8 = *(const bf16x8*)(wh + (nt*16 + l15)*328 + k0);
      bf16x8 bl8 = *(const bf16x8*)(wl + (nt*16 + l15)*328 + k0);
      #pragma unroll
      for (int mt = 0; mt < 2; ++mt){
        acc[mt][nt] = mfma16(ah[mt], bh8, acc[mt][nt]);
        acc[mt][nt] = mfma16(ah[mt], bl8, acc[mt][nt]);
        acc[mt][nt] = mfma16(al[mt], bh8, acc[mt][nt]);
      }
    }
  }
  #pragma unroll
  for (int nt = 0; nt < 4; ++nt){
    int o = obase + nt*16 + l15;
    float bias = bx[o] + bh[o];
    #pragma unroll
    for (int mt = 0; mt < 2; ++mt){
      int b0 = w*32 + mt*16 + lr4;
      *(f32x4*)(P + ((long long)t*1024 + o)*BATCH + b0) = acc[mt][nt] + bias;
    }
  }
}

// ---- P_f[t][b][m] = x_t[b,:]·W_fx[m,:] + b_fx[m] + b_Uh[m] ----
__global__ __launch_bounds__(256) void proj_f(const unsigned short* __restrict__ xh,
                                              const unsigned short* __restrict__ xl,
                                              const unsigned short* __restrict__ wxh,
                                              const unsigned short* __restrict__ wxl,
                                              const float* __restrict__ bf,
                                              const float* __restrict__ bu,
                                              float* __restrict__ Pf){
  const int t = blockIdx.x, mbase = blockIdx.y * 64;
  __shared__ unsigned short wh[64*328];
  __shared__ unsigned short wl[64*328];
  for (int c = threadIdx.x; c < 64*40; c += 256){
    int r = c / 40, c8 = (c % 40) * 8;
    *(bf16x8*)(wh + r*328 + c8) = *(const bf16x8*)(wxh + (1024 + mbase + r)*KP + c8);
    *(bf16x8*)(wl + r*328 + c8) = *(const bf16x8*)(wxl + (1024 + mbase + r)*KP + c8);
  }
  __syncthreads();
  const int lane = threadIdx.x & 63, w = threadIdx.x >> 6;
  const int l15 = lane & 15, lk = (lane >> 4) << 3, lr4 = (lane >> 4) << 2;
  f32x4 acc[4][2] = {};
  const unsigned short* xbh = xh + (long long)t * BATCH * KP;
  const unsigned short* xbl = xl + (long long)t * BATCH * KP;
  for (int ks = 0; ks < 10; ++ks){
    int k0 = ks*32 + lk;
    bf16x8 bh8[2], bl8[2];
    #pragma unroll
    for (int nt = 0; nt < 2; ++nt){
      int b = w*32 + nt*16 + l15;
      bh8[nt] = *(const bf16x8*)(xbh + b*KP + k0);
      bl8[nt] = *(const bf16x8*)(xbl + b*KP + k0);
    }
    #pragma unroll
    for (int mt = 0; mt < 4; ++mt){
      bf16x8 ah = *(const bf16x8*)(wh + (mt*16 + l15)*328 + k0);
      bf16x8 al = *(const bf16x8*)(wl + (mt*16 + l15)*328 + k0);
      #pragma unroll
      for (int nt = 0; nt < 2; ++nt){
        acc[mt][nt] = mfma16(ah, bh8[nt], acc[mt][nt]);
        acc[mt][nt] = mfma16(ah, bl8[nt], acc[mt][nt]);
        acc[mt][nt] = mfma16(al, bh8[nt], acc[mt][nt]);
      }
    }
  }
  #pragma unroll
  for (int mt = 0; mt < 4; ++mt){
    int m0 = mbase + mt*16 + lr4;
    f32x4 bias = *(const f32x4*)(bf + m0);
    f32x4 bias2 = *(const f32x4*)(bu + m0);
    #pragma unroll
    for (int nt = 0; nt < 2; ++nt){
      int b = w*32 + nt*16 + l15;
      *(f32x4*)(Pf + ((long long)t*BATCH + b)*MEM + m0) = acc[mt][nt] + bias + bias2;
    }
  }
}

// ---- persistent GRU scan: 64 WGs x 512 threads ----
// h2/rh2: ushort[128][1024], row = hi(512) ++ lo(512). Cross-WG traffic via
// sc0 sc1 (MALL); loads batched in inline asm (32 in flight, ONE vmcnt(0)).
__global__ __launch_bounds__(512, 2) void scan_kernel(
    const float* __restrict__ Wiouh, const float* __restrict__ Wuh,
    const float* __restrict__ Piou, const float* __restrict__ Pf,
    unsigned short* __restrict__ h2, unsigned short* __restrict__ rh2,
    float* __restrict__ out, unsigned* __restrict__ slots)
{
  const int g = blockIdx.x;
  const int tid = threadIdx.x;
  const int lane = tid & 63, w = tid >> 6;
  const int l15 = lane & 15, lk = (lane >> 4) << 3, lr4 = (lane >> 4) << 2;

  __shared__ unsigned short zr_h[16*520];   // rows 0-7: W_iouh z-slice, 8-15: r-slice
  __shared__ unsigned short zr_l[16*520];
  __shared__ unsigned short wu_h[16*520];   // rows 0-7: W_Uh slice, 8-15: zeros
  __shared__ unsigned short wu_l[16*520];
  __shared__ float          z_lds[BATCH*8];
  __shared__ unsigned short fl_h[BATCH*8];
  __shared__ unsigned short fl_l[BATCH*8];
  __shared__ float          hn_lds[8*BATCH];

  for (int idx = tid; idx < 16*512; idx += 512){
    int r = idx >> 9, k = idx & 511;
    float vz = (r < 8) ? Wiouh[(g*8 + r)*512 + k]
                       : Wiouh[(512 + g*8 + (r - 8))*512 + k];
    unsigned short hz = f2bf(vz);
    zr_h[r*520 + k] = hz;
    zr_l[r*520 + k] = f2bf(vz - bf2f(hz));
    float vu = (r < 8) ? Wuh[(g*8 + r)*512 + k] : 0.0f;
    unsigned short hu = f2bf(vu);
    wu_h[r*520 + k] = hu;
    wu_l[r*520 + k] = f2bf(vu - bf2f(hu));
  }
  for (int idx = tid; idx < 8*BATCH; idx += 512) hn_lds[idx] = 0.0f;
  __syncthreads();

  const bool is_z = (l15 < 8);
  const int o_p = is_z ? (g*8 + l15) : (512 + g*8 + (l15 - 8)); // P_iou row
  const bool valid2 = (lane >> 4) < 2;
  const int b0 = w*16 + lr4;
  const int b2 = w*16 + l15;          // batch row for A(phase1) / B(phase2)
  const int m0g = g*8 + lr4;
  const unsigned short* ph = h2  + b2*1024 + lk;
  const unsigned short* pr = rh2 + b2*1024 + lk;
  unsigned gen = 0;

  f32x4 p1 = *(const f32x4*)(Piou + (long long)o_p*BATCH + b0);  // t = 0

  for (int t = 0; t < T_STEPS; ++t){
    // ================= phase 1: iou = h @ W_zr^T =================
    {
      bf16x8 Ah[16], Al[16];
      __builtin_amdgcn_sched_barrier(0);
      ld_row_batch(ph, Ah, Al);
      asm volatile("s_waitcnt vmcnt(0)" ::: "memory");
      __builtin_amdgcn_sched_barrier(0);
      f32x4 acc1 = {0.f,0.f,0.f,0.f};
      #pragma unroll
      for (int ks = 0; ks < 16; ++ks){
        int k0 = ks*32 + lk;
        bf16x8 b_h = *(const bf16x8*)(zr_h + l15*520 + k0);
        bf16x8 b_l = *(const bf16x8*)(zr_l + l15*520 + k0);
        acc1 = mfma16(Ah[ks], b_h, acc1);
        acc1 = mfma16(Ah[ks], b_l, acc1);
        acc1 = mfma16(Al[ks], b_h, acc1);
      }
      if (is_z){
        #pragma unroll
        for (int j = 0; j < 4; ++j){
          float zv = sigm(acc1[j] + p1[j]);
          z_lds[(b0 + j)*8 + l15] = zv;
        }
      } else {
        #pragma unroll
        for (int j = 0; j < 4; ++j){
          float rv = sigm(acc1[j] + p1[j]);
          float rh = rv * hn_lds[(l15 - 8)*BATCH + b0 + j];
          unsigned short hi = f2bf(rh);
          fl_h[(b0 + j)*8 + (l15 - 8)] = hi;
          fl_l[(b0 + j)*8 + (l15 - 8)] = f2bf(rh - bf2f(hi));
        }
      }
    }
    __syncthreads();
    { // flush rh slice to MALL: 512 threads x 8B write-through
      int b = tid >> 2, q = tid & 3;
      int plane = q >> 1, half = q & 1;
      const unsigned short* src = (plane ? fl_l : fl_h) + b*8 + half*4;
      unsigned long long v = *(const unsigned long long*)src;
      st8_sc(rh2 + b*1024 + plane*512 + g*8 + half*4, v);
    }
    __syncthreads();                     // per-wave vmcnt(0) drain before s_barrier
    ++gen;
    if (tid == 0) st4_sc(&slots[g], gen);
    f32x4 p2 = {0.f,0.f,0.f,0.f};
    if (valid2) p2 = *(const f32x4*)(Pf + ((long long)t*BATCH + b2)*MEM + m0g);
    if (tid < 64){
      for (;;){
        unsigned v = ld4_sc(&slots[tid]);
        if (__all((int)(v >= gen))) break;
        __builtin_amdgcn_s_sleep(2);
      }
    }
    __syncthreads();
    asm volatile("" ::: "memory");

    // ================= phase 2: u = rh @ W_U^T =================
    {
      bf16x8 Bh[16], Bl[16];
      __builtin_amdgcn_sched_barrier(0);
      ld_row_batch(pr, Bh, Bl);
      asm volatile("s_waitcnt vmcnt(0)" ::: "memory");
      __builtin_amdgcn_sched_barrier(0);
      f32x4 acc2 = {0.f,0.f,0.f,0.f};
      #pragma unroll
      for (int ks = 0; ks < 16; ++ks){
        int k0 = ks*32 + lk;
        bf16x8 a_h = *(const bf16x8*)(wu_h + l15*520 + k0);
        bf16x8 a_l = *(const bf16x8*)(wu_l + l15*520 + k0);
        acc2 = mfma16(a_h, Bh[ks], acc2);
        acc2 = mfma16(a_h, Bl[ks], acc2);
        acc2 = mfma16(a_l, Bh[ks], acc2);
      }
      if (valid2){
        f32x4 zz = *(const f32x4*)(&z_lds[b2*8 + lr4]);
        f32x4 hn;
        u16x4 nh, nl;
        #pragma unroll
        for (int j = 0; j < 4; ++j){
          float h_old = hn_lds[(lr4 + j)*BATCH + b2];
          float ht = tanh_(acc2[j] + p2[j]);
          float hv = (1.0f - zz[j])*h_old + zz[j]*ht;
          hn[j] = hv;
          unsigned short nhi = f2bf(hv);
          nh[j] = nhi;
          nl[j] = f2bf(hv - bf2f(nhi));
          hn_lds[(lr4 + j)*BATCH + b2] = hv;
        }
        *(f32x4*)(out + ((long long)t*BATCH + b2)*MEM + m0g) = hn;
        union { u16x4 s; unsigned long long q; } uh, ul;
        uh.s = nh; ul.s = nl;
        st8_sc(h2 + b2*1024 + m0g, uh.q);          // hi plane
        st8_sc(h2 + b2*1024 + 512 + m0g, ul.q);    // lo plane
      }
    }
    __syncthreads();                     // drain h/out stores
    ++gen;
    if (tid == 0) st4_sc(&slots[g], gen);
    if (t + 1 < T_STEPS)
      p1 = *(const f32x4*)(Piou + ((long long)(t+1)*1024 + o_p)*BATCH + b0);
    if (tid < 64){
      for (;;){
        unsigned v = ld4_sc(&slots[tid]);
        if (__all((int)(v >= gen))) break;
        __builtin_amdgcn_s_sleep(2);
      }
    }
    __syncthreads();
    asm volatile("" ::: "memory");
  }
}

extern "C" void kernel_launch(void* const* d_in, const int* in_sizes, int n_in,
                              void* d_out, int out_size, void* d_ws, size_t ws_size,
                              hipStream_t stream){
  (void)in_sizes; (void)n_in; (void)out_size; (void)ws_size;
  const float* x     = (const float*)d_in[0];
  const float* Wioux = (const float*)d_in[1];
  const float* bioux = (const float*)d_in[2];
  const float* Wiouh = (const float*)d_in[3];
  const float* biouh = (const float*)d_in[4];
  const float* Wfx   = (const float*)d_in[5];
  const float* bfx   = (const float*)d_in[6];
  const float* Wuh   = (const float*)d_in[7];
  const float* buh   = (const float*)d_in[8];
  float* out = (float*)d_out;

  char* ws = (char*)d_ws;
  size_t off = 0;
  auto alloc = [&](size_t bytes) -> void* {
    void* p = ws + off;
    off += (bytes + 255) & ~(size_t)255;
    return p;
  };
  float* Piou = (float*)alloc((size_t)T_STEPS*1024*BATCH*sizeof(float)); // 268 MB
  float* Pf   = (float*)alloc((size_t)T_STEPS*BATCH*MEM*sizeof(float));  // 134 MB
  unsigned short* xh = (unsigned short*)alloc((size_t)T_STEPS*BATCH*KP*2);
  unsigned short* xl = (unsigned short*)alloc((size_t)T_STEPS*BATCH*KP*2);
  unsigned short* wxh = (unsigned short*)alloc((size_t)1536*KP*2);
  unsigned short* wxl = (unsigned short*)alloc((size_t)1536*KP*2);
  unsigned short* h2  = (unsigned short*)alloc((size_t)BATCH*1024*2);
  unsigned short* rh2 = (unsigned short*)alloc((size_t)BATCH*1024*2);
  unsigned* slots = (unsigned*)alloc(256);

  hipMemsetAsync(h2, 0, (size_t)BATCH*1024*2, stream);   // h0 = 0
  hipMemsetAsync(slots, 0, 256, stream);                 // barrier slots

  prep_x<<<2048, 256, 0, stream>>>(x, xh, xl);
  prep_w<<<512, 256, 0, stream>>>(Wioux, Wfx, wxh, wxl);
  proj_iou<<<dim3(T_STEPS, 16), 256, 0, stream>>>(xh, xl, wxh, wxl, bioux, biouh, Piou);
  proj_f<<<dim3(T_STEPS, 8), 256, 0, stream>>>(xh, xl, wxh, wxl, bfx, buh, Pf);
  scan_kernel<<<NWG, 512, 0, stream>>>(Wiouh, Wuh, Piou, Pf, h2, rh2, out, slots);
}